// Round 1
// baseline (13.042 us; speedup 1.0000x reference)
//
#include <hip/hip_runtime.h>

// Closed-form collapse of the 4-wire QNN circuit:
//   z_k = cos(x_k)*cos(x_{k+4})*cos(t) - sin(x_k)*sin(t),  t = theta_rx[0]
//   expz = [z0, z0*z1, z0*z1*z2, z0*z1*z2*z3];  out = softmax(expz)
// (final RZ layer and theta_rz are provably irrelevant to probabilities;
//  CNOT chain is a basis permutation of a product state.)

__global__ __launch_bounds__(256) void qnn_closed_form_kernel(
    const float* __restrict__ x,          // [n, 8]
    const float* __restrict__ theta_rx,   // [1]
    float* __restrict__ out,              // [n, 4]
    int n)
{
    float t = theta_rx[0];          // broadcast scalar load (L2-cached)
    float st, ct;
    __sincosf(t, &st, &ct);

    int stride = gridDim.x * blockDim.x;
    for (int i = blockIdx.x * blockDim.x + threadIdx.x; i < n; i += stride) {
        const float4 xa = *reinterpret_cast<const float4*>(x + (size_t)i * 8);
        const float4 xb = *reinterpret_cast<const float4*>(x + (size_t)i * 8 + 4);
        const float a[4] = {xa.x, xa.y, xa.z, xa.w};
        const float b[4] = {xb.x, xb.y, xb.z, xb.w};

        float z[4];
        #pragma unroll
        for (int k = 0; k < 4; ++k) {
            float sa, ca;
            __sincosf(a[k], &sa, &ca);
            float cb = __cosf(b[k]);
            z[k] = ca * cb * ct - sa * st;
        }

        float e0 = z[0];
        float e1 = e0 * z[1];
        float e2 = e1 * z[2];
        float e3 = e2 * z[3];

        // numerically-stable 4-way softmax (values are in [-1,1] anyway)
        float m  = fmaxf(fmaxf(e0, e1), fmaxf(e2, e3));
        float p0 = __expf(e0 - m);
        float p1 = __expf(e1 - m);
        float p2 = __expf(e2 - m);
        float p3 = __expf(e3 - m);
        float inv = 1.0f / (p0 + p1 + p2 + p3);

        float4 o = make_float4(p0 * inv, p1 * inv, p2 * inv, p3 * inv);
        *reinterpret_cast<float4*>(out + (size_t)i * 4) = o;
    }
}

extern "C" void kernel_launch(void* const* d_in, const int* in_sizes, int n_in,
                              void* d_out, int out_size, void* d_ws, size_t ws_size,
                              hipStream_t stream) {
    const float* x        = (const float*)d_in[0];   // [b, 8] float32
    const float* theta_rx = (const float*)d_in[1];   // [1]   float32
    // d_in[2] = theta_rz: provably unused (diagonal gates drop out of |amp|^2)
    float* out = (float*)d_out;                      // [b, 4] float32

    int n = in_sizes[0] / 8;
    int block = 256;
    int grid = (n + block - 1) / block;
    if (grid > 2048) grid = 2048;                    // grid-stride the rest
    qnn_closed_form_kernel<<<grid, block, 0, stream>>>(x, theta_rx, out, n);
}